// Round 8
// baseline (2956.931 us; speedup 1.0000x reference)
//
#include <hip/hip_runtime.h>

typedef unsigned short u16;
typedef unsigned int   u32;

#define B_     4
#define L_     392
#define T_     1568   // B_*L_
#define DM     384
#define DI     768
#define DS     16
#define DTR    24
#define DEPTH_ 24
#define NPATCH 196
#define NC     28    // scan chunks
#define CL     14    // chunk length (NC*CL == L_)

// xproj_conv: K-split 8 -> 96 d's per block; LDS row pitch 104 (208B = 13*16B)
#define XKC    96
#define XPAD   104
// gemm_out: K-split 4 -> 192 d's per block; LDS row pitch 200 u16 (400B = 25*16B)
#define OKC    192
#define OPAD   200

typedef __bf16 bf16x8 __attribute__((ext_vector_type(8)));
typedef float  f32x4  __attribute__((ext_vector_type(4)));
typedef u16    u16x4  __attribute__((ext_vector_type(4)));

__device__ __forceinline__ u16 f2bf(float f) {
  union { float f; u32 u; } v; v.f = f;
  return (u16)((v.u + 0x7fffu + ((v.u >> 16) & 1u)) >> 16);  // RNE
}
__device__ __forceinline__ float bf2f(u16 h) {
  union { u32 u; float f; } v; v.u = (u32)h << 16; return v.f;
}

// ---------------- fp32 -> bf16 bulk convert, vectorized, 4 segments ----------------
__global__ __launch_bounds__(256) void cvt4v_kernel(const float* __restrict__ s0, u16* __restrict__ o0, int m0,
                                                    const float* __restrict__ s1, u16* __restrict__ o1, int m1,
                                                    const float* __restrict__ s2, u16* __restrict__ o2, int m2,
                                                    const float* __restrict__ s3, u16* __restrict__ o3, int m3) {
  int i = blockIdx.x * 256 + threadIdx.x;   // index in float4 units
  const float* s; u16* o;
  if (i < m0)      { s = s0; o = o0; }
  else { i -= m0;
  if (i < m1)      { s = s1; o = o1; }
  else { i -= m1;
  if (i < m2)      { s = s2; o = o2; }
  else { i -= m2;
  if (i < m3)      { s = s3; o = o3; }
  else return; } } }
  float4 v = ((const float4*)s)[i];
  u16x4 r;
  r.x = f2bf(v.x); r.y = f2bf(v.y); r.z = f2bf(v.z); r.w = f2bf(v.w);
  ((u16x4*)o)[i] = r;
}

// ---------------- im2col for patch embed (both z and x) ----------------
__global__ __launch_bounds__(256) void imcol_kernel(const float* __restrict__ z,
                                                    const float* __restrict__ x,
                                                    u16* __restrict__ out) {
  int idx = blockIdx.x * 256 + threadIdx.x;        // t*768 + k
  int t = idx / 768, k = idx - t * 768;
  int b = t / L_, l = t - b * L_;
  const float* img = (l < NPATCH) ? z : x;
  int p  = (l < NPATCH) ? l : l - NPATCH;
  int py = p / 14, px = p - py * 14;
  int ic = k >> 8, rem = k & 255, i = rem >> 4, j = rem & 15;
  float v = img[((size_t)b * 3 + ic) * 50176 + (size_t)(py * 16 + i) * 224 + (px * 16 + j)];
  out[idx] = f2bf(v);
}

// ---------------- generic bf16 MFMA GEMM (patch embed only) ----------------
__global__ __launch_bounds__(256) void gemm_bf16(const u16* __restrict__ A,
                                                 const u16* __restrict__ W,
                                                 float* __restrict__ outf,
                                                 int M, int N, int K) {
  int wave = threadIdx.x >> 6;
  int lane = threadIdx.x & 63;
  int r = lane & 15, quad = lane >> 4;
  int m_base = blockIdx.x * 64;
  int n_base = blockIdx.y * 64 + wave * 16;

  const u16* aptr[4];
#pragma unroll
  for (int mi = 0; mi < 4; ++mi) {
    int row = m_base + mi * 16 + r; if (row > M - 1) row = M - 1;
    aptr[mi] = A + (size_t)row * K + quad * 8;
  }
  int wcol = n_base + r; if (wcol > N - 1) wcol = N - 1;
  const u16* wptr = W + (size_t)wcol * K + quad * 8;

  f32x4 acc[4] = {f32x4{0,0,0,0}, f32x4{0,0,0,0}, f32x4{0,0,0,0}, f32x4{0,0,0,0}};
  for (int k0 = 0; k0 < K; k0 += 32) {
    bf16x8 bfrag = *(const bf16x8*)(wptr + k0);
#pragma unroll
    for (int mi = 0; mi < 4; ++mi) {
      bf16x8 afrag = *(const bf16x8*)(aptr[mi] + k0);
      acc[mi] = __builtin_amdgcn_mfma_f32_16x16x32_bf16(afrag, bfrag, acc[mi], 0, 0, 0);
    }
  }
  int ccol = n_base + r;
  if (ccol < N) {
#pragma unroll
    for (int mi = 0; mi < 4; ++mi) {
#pragma unroll
      for (int rr = 0; rr < 4; ++rr) {
        int crow = m_base + mi * 16 + quad * 4 + rr;
        if (crow < M) outf[(size_t)crow * N + ccol] = acc[mi][rr];
      }
    }
  }
}

// ---------------- fused LayerNorm + in_proj GEMM ----------------
// xzt[1536][T] = inWb[1536,384] · LN(h)[T,384]^T, bf16 out. grid (24, 25).
__global__ __launch_bounds__(256) void gemm_ln(const float* __restrict__ h,
                                               const float* __restrict__ lw,
                                               const float* __restrict__ lb,
                                               const u16* __restrict__ Wt,
                                               u16* __restrict__ xzt) {
  __shared__ u16 atile[64][392];   // 784B row = 49*16B: aligned b128, 2-way banks
  __shared__ float ps[4][64], ps2[4][64], smu[64], srs[64];
  int tid = threadIdx.x;
  int tok = tid & 63, q = tid >> 6;
  int tok0 = blockIdx.y * 64;
  int tg = tok0 + tok; if (tg > T_ - 1) tg = T_ - 1;
  const float* hrow = h + (size_t)tg * DM + q * 96;

  float s = 0.f, s2 = 0.f;
#pragma unroll
  for (int i = 0; i < 24; ++i) {
    float4 v = *(const float4*)(hrow + i * 4);
    s  += v.x + v.y + v.z + v.w;
    s2 += v.x * v.x + v.y * v.y + v.z * v.z + v.w * v.w;
  }
  ps[q][tok] = s; ps2[q][tok] = s2;
  __syncthreads();
  if (tid < 64) {
    float ts  = ps[0][tid] + ps[1][tid] + ps[2][tid] + ps[3][tid];
    float ts2 = ps2[0][tid] + ps2[1][tid] + ps2[2][tid] + ps2[3][tid];
    float mu  = ts * (1.f / DM);
    float var = ts2 * (1.f / DM) - mu * mu;
    smu[tid] = mu; srs[tid] = rsqrtf(var + 1e-5f);
  }
  __syncthreads();
  {
    float mu = smu[tok], rs = srs[tok];
#pragma unroll
    for (int i = 0; i < 24; ++i) {
      int k = q * 96 + i * 4;
      float4 v  = *(const float4*)(hrow + i * 4);
      float4 w4 = *(const float4*)(lw + k);
      float4 b4 = *(const float4*)(lb + k);
      u16x4 rr;
      rr.x = f2bf((v.x - mu) * rs * w4.x + b4.x);
      rr.y = f2bf((v.y - mu) * rs * w4.y + b4.y);
      rr.z = f2bf((v.z - mu) * rs * w4.z + b4.z);
      rr.w = f2bf((v.w - mu) * rs * w4.w + b4.w);
      *(u16x4*)&atile[tok][k] = rr;
    }
  }
  __syncthreads();

  int lane = tid & 63;
  int r = lane & 15, quad = lane >> 4;
  int m_base = blockIdx.x * 64;
  const u16* aptr[4];
#pragma unroll
  for (int mi = 0; mi < 4; ++mi)
    aptr[mi] = Wt + (size_t)(m_base + mi * 16 + r) * DM + quad * 8;
  const u16* lptr = &atile[q * 16 + r][quad * 8];

  f32x4 acc[4] = {f32x4{0,0,0,0}, f32x4{0,0,0,0}, f32x4{0,0,0,0}, f32x4{0,0,0,0}};
#pragma unroll
  for (int k0 = 0; k0 < DM; k0 += 32) {
    bf16x8 bfrag = *(const bf16x8*)(lptr + k0);
#pragma unroll
    for (int mi = 0; mi < 4; ++mi) {
      bf16x8 afrag = *(const bf16x8*)(aptr[mi] + k0);
      acc[mi] = __builtin_amdgcn_mfma_f32_16x16x32_bf16(afrag, bfrag, acc[mi], 0, 0, 0);
    }
  }
  int ccol = tok0 + q * 16 + r;
  if (ccol < T_) {
#pragma unroll
    for (int mi = 0; mi < 4; ++mi) {
#pragma unroll
      for (int rr2 = 0; rr2 < 4; ++rr2) {
        int crow = m_base + mi * 16 + quad * 4 + rr2;
        xzt[(size_t)crow * T_ + ccol] = f2bf(acc[mi][rr2]);
      }
    }
  }
}

// ---------------- fused conv3+SiLU + x_proj GEMM ----------------
// dbl[T,56] += conv(xzt)·xpW^T over d-slice. grid (25, 1, 8), atomic epilogue.
__global__ __launch_bounds__(256) void xproj_conv(const u16* __restrict__ xzt,
                                                  const float* __restrict__ cw,
                                                  const float* __restrict__ cb,
                                                  const u16* __restrict__ Wx,
                                                  float* __restrict__ dbl) {
  __shared__ u16 tile[64][XPAD];   // 208B row = 13*16B
  int t0 = blockIdx.x * 64;
  int kbeg = blockIdx.z * XKC;
  int tid = threadIdx.x;
  int tl = tid & 63, rq = tid >> 6;
  int t = t0 + tl;
  int tc = (t < T_) ? t : T_ - 1;
  int l = tc % L_;
  for (int kkb = rq * 2; kkb < XKC; kkb += 8) {
    u32 pack = 0;
#pragma unroll
    for (int ss = 0; ss < 2; ++ss) {
      int d = kbeg + kkb + ss;
      const u16* row = xzt + (size_t)d * T_ + tc;
      float acc = cb[d] + cw[d * 3 + 2] * bf2f(row[0]);
      if (l >= 1) acc += cw[d * 3 + 1] * bf2f(row[-1]);
      if (l >= 2) acc += cw[d * 3 + 0] * bf2f(row[-2]);
      float v = acc / (1.f + __expf(-acc));
      pack |= (u32)f2bf(v) << (16 * ss);
    }
    *(u32*)&tile[tl][kkb] = pack;
  }
  __syncthreads();

  int wave = tid >> 6, lane = tid & 63;
  int r = lane & 15, quad = lane >> 4;
  int wcol = wave * 16 + r; int wc = (wcol < 56) ? wcol : 55;
  const u16* wptr = Wx + (size_t)wc * DI + kbeg + quad * 8;

  f32x4 acc4[4] = {f32x4{0,0,0,0}, f32x4{0,0,0,0}, f32x4{0,0,0,0}, f32x4{0,0,0,0}};
#pragma unroll
  for (int k0 = 0; k0 < XKC; k0 += 32) {
    bf16x8 bfrag = *(const bf16x8*)(wptr + k0);
#pragma unroll
    for (int mi = 0; mi < 4; ++mi) {
      bf16x8 afrag = *(const bf16x8*)&tile[mi * 16 + r][k0 + quad * 8];
      acc4[mi] = __builtin_amdgcn_mfma_f32_16x16x32_bf16(afrag, bfrag, acc4[mi], 0, 0, 0);
    }
  }
  if (wcol < 56) {
#pragma unroll
    for (int mi = 0; mi < 4; ++mi) {
#pragma unroll
      for (int rr = 0; rr < 4; ++rr) {
        int crow = t0 + mi * 16 + quad * 4 + rr;
        if (crow < T_) atomicAdd(&dbl[(size_t)crow * 56 + wcol], acc4[mi][rr]);
      }
    }
  }
}

// ---------------- fused transpose + out_proj GEMM ----------------
// h[T,384] += y^T·outW^T over d-slice. grid (25, 6, 4), atomic epilogue.
__global__ __launch_bounds__(256) void gemm_out(const u16* __restrict__ yt,
                                                const u16* __restrict__ Wo,
                                                float* __restrict__ h) {
  __shared__ u16 tile[64][OPAD];
  int t0 = blockIdx.x * 64;
  int n0 = blockIdx.y * 64;
  int kbeg = blockIdx.z * OKC;
  int tid = threadIdx.x;
  {
    int tl2 = tid & 31, rq = tid >> 5;   // 8 rows per pass
    for (int kk = rq; kk < OKC; kk += 8) {
      int d = kbeg + kk;
      u32 v = *(const u32*)(yt + (size_t)d * T_ + t0 + tl2 * 2);
      tile[tl2 * 2][kk]     = (u16)v;
      tile[tl2 * 2 + 1][kk] = (u16)(v >> 16);
    }
  }
  __syncthreads();

  int wave = tid >> 6, lane = tid & 63;
  int r = lane & 15, quad = lane >> 4;
  const u16* wptr = Wo + (size_t)(n0 + wave * 16 + r) * DI + kbeg + quad * 8;

  f32x4 acc[4] = {f32x4{0,0,0,0}, f32x4{0,0,0,0}, f32x4{0,0,0,0}, f32x4{0,0,0,0}};
#pragma unroll
  for (int k0 = 0; k0 < OKC; k0 += 32) {
    bf16x8 bfrag = *(const bf16x8*)(wptr + k0);
#pragma unroll
    for (int mi = 0; mi < 4; ++mi) {
      bf16x8 afrag = *(const bf16x8*)&tile[mi * 16 + r][k0 + quad * 8];
      acc[mi] = __builtin_amdgcn_mfma_f32_16x16x32_bf16(afrag, bfrag, acc[mi], 0, 0, 0);
    }
  }
  int ccol = n0 + wave * 16 + r;
#pragma unroll
  for (int mi = 0; mi < 4; ++mi) {
#pragma unroll
    for (int rr = 0; rr < 4; ++rr) {
      int crow = t0 + mi * 16 + quad * 4 + rr;
      if (crow < T_) atomicAdd(&h[(size_t)crow * DM + ccol], acc[mi][rr]);
    }
  }
}

// ---------------- add patch bias + positional embedding; zero both dbl buffers ----------------
__global__ __launch_bounds__(256) void biaspos_kernel(float* __restrict__ h,
                                                      const float* __restrict__ pb,
                                                      const float* __restrict__ pos,
                                                      float* __restrict__ dblz) {
  int idx = blockIdx.x * 256 + threadIdx.x;  // t*384 + c
  if (idx < 2 * T_ * 56) dblz[idx] = 0.f;
  int t = idx / DM, c = idx - t * DM;
  int p = (t % L_) % NPATCH;
  h[idx] += pb[c] + pos[(size_t)(1 + p) * DM + c];
}

// ---------------- LayerNorm over DM per token (final only) ----------------
__global__ __launch_bounds__(384) void ln_kernel(const float* __restrict__ x,
                                                 const float* __restrict__ w,
                                                 const float* __restrict__ b,
                                                 float* __restrict__ out_f) {
  int t = blockIdx.x;
  int i = threadIdx.x;
  float v = x[(size_t)t * DM + i];
  float s = v, s2 = v * v;
#pragma unroll
  for (int o = 32; o; o >>= 1) { s += __shfl_xor(s, o); s2 += __shfl_xor(s2, o); }
  __shared__ float ls[6], ls2[6];
  int wv = i >> 6;
  if ((i & 63) == 0) { ls[wv] = s; ls2[wv] = s2; }
  __syncthreads();
  float ts = 0.f, ts2 = 0.f;
#pragma unroll
  for (int j = 0; j < 6; ++j) { ts += ls[j]; ts2 += ls2[j]; }
  float mu  = ts * (1.f / DM);
  float var = ts2 * (1.f / DM) - mu * mu;
  float rs  = rsqrtf(var + 1e-5f);
  out_f[(size_t)t * DM + i] = (v - mu) * rs * w[i] + b[i];
}

// ---------------- chunked selective scan v4: NC=28, CL=14, 448 threads ----------------
// Recomputes conv row; fused dt-proj/softplus + silu(z); dA/dBu register-cached.
// Zeroes the NEXT layer's dbl buffer.
__global__ __launch_bounds__(448) void scan_kernel(const u16* __restrict__ xzt,
                                                   const float* __restrict__ dbl,
                                                   const float* __restrict__ cw,
                                                   const float* __restrict__ cb,
                                                   const float* __restrict__ dtW,
                                                   const float* __restrict__ dtB,
                                                   const float* __restrict__ Alog,
                                                   const float* __restrict__ Dp,
                                                   u16* __restrict__ yt,
                                                   float* __restrict__ dblz) {
  int bd = blockIdx.x;          // b*DI + d
  int d  = bd % DI;
  int b  = bd / DI;
  int tid = threadIdx.x;
  int n = tid & 15, c = tid >> 4;   // c in [0,28)

  __shared__ float dtsh[L_];
  __shared__ float zsh[L_];
  __shared__ float xcsh[L_];
  __shared__ float Psh[NC][DS], Ssh[NC][DS], Hsh[NC][DS];
  __shared__ u16 ysh[L_];

  // zero slice of next dbl buffer (29 floats per block)
  {
    int i0 = blockIdx.x * 29 + tid;
    if (tid < 29 && i0 < T_ * 56) dblz[i0] = 0.f;
  }

  // cooperative: conv row (recompute), dt projection + softplus, silu(z) — one pass
  const float* wr = dtW + (size_t)d * DTR;   // block-uniform -> scalar loads
  float bias = dtB[d];
  float w0 = cw[d * 3 + 0], w1 = cw[d * 3 + 1], w2 = cw[d * 3 + 2], cbd = cb[d];
  const u16* xrow = xzt + (size_t)d * T_ + b * L_;
  const u16* zrow = xzt + (size_t)(DI + d) * T_ + b * L_;
  if (tid < L_) {
    int l = tid;
    const float* dr = dbl + (size_t)(b * L_ + l) * 56;
    float s = bias;
#pragma unroll
    for (int j = 0; j < DTR; ++j) s += dr[j] * wr[j];
    dtsh[l] = (s > 20.f) ? s : log1pf(__expf(s));
    float zv = bf2f(zrow[l]);
    zsh[l] = zv / (1.f + __expf(-zv));
    float a = cbd + w2 * bf2f(xrow[l]);
    if (l >= 1) a += w1 * bf2f(xrow[l - 1]);
    if (l >= 2) a += w0 * bf2f(xrow[l - 2]);
    xcsh[l] = a / (1.f + __expf(-a));
  }
  float A  = -__expf(Alog[(size_t)d * DS + n]);
  float Dd = Dp[d];
  __syncthreads();

  int tb = b * L_ + c * CL;
  const float* Bp = dbl + (size_t)tb * 56 + DTR + n;
  const float* Cp = Bp + DS;

  float dA[CL], dBu[CL];
  {
    float P = 1.f, S = 0.f;
#pragma unroll
    for (int l = 0; l < CL; ++l) {
      float dtv = dtsh[c * CL + l];
      float xcv = xcsh[c * CL + l];
      float Bv  = Bp[l * 56];
      float e = __expf(dtv * A);
      float u = dtv * xcv * Bv;
      dA[l] = e; dBu[l] = u;
      P *= e;
      S = e * S + u;
    }
    Psh[c][n] = P; Ssh[c][n] = S;
  }
  __syncthreads();
  if (tid < DS) {   // thread n: serial combine over 28 chunks
    float hh = 0.f;
#pragma unroll
    for (int cc = 0; cc < NC; ++cc) {
      Hsh[cc][tid] = hh;
      hh = Psh[cc][tid] * hh + Ssh[cc][tid];
    }
  }
  __syncthreads();
  {
    float hh = Hsh[c][n];
#pragma unroll
    for (int l = 0; l < CL; ++l) {
      hh = dA[l] * hh + dBu[l];
      float p = hh * Cp[l * 56];
      p += __shfl_xor(p, 1); p += __shfl_xor(p, 2);
      p += __shfl_xor(p, 4); p += __shfl_xor(p, 8);
      if (n == 0) {
        int ll = c * CL + l;
        ysh[ll] = f2bf((p + Dd * xcsh[ll]) * zsh[ll]);
      }
    }
  }
  __syncthreads();
  if (tid < 196) {  // 392 u16 = 196 dwords, contiguous coalesced row store
    ((u32*)(yt + (size_t)d * T_ + b * L_))[tid] = ((const u32*)ysh)[tid];
  }
}

extern "C" void kernel_launch(void* const* d_in, const int* in_sizes, int n_in,
                              void* d_out, int out_size, void* d_ws, size_t ws_size,
                              hipStream_t stream) {
  const float* z      = (const float*)d_in[0];
  const float* x      = (const float*)d_in[1];
  const float* patchW = (const float*)d_in[2];
  const float* patchB = (const float*)d_in[3];
  const float* pos    = (const float*)d_in[4];
  const float* normW  = (const float*)d_in[5];
  const float* normB  = (const float*)d_in[6];
  const float* inW    = (const float*)d_in[7];
  const float* convW  = (const float*)d_in[8];
  const float* convB  = (const float*)d_in[9];
  const float* xprojW = (const float*)d_in[10];
  const float* dtW    = (const float*)d_in[11];
  const float* dtB    = (const float*)d_in[12];
  const float* Alog   = (const float*)d_in[13];
  const float* Dpar   = (const float*)d_in[14];
  const float* outW   = (const float*)d_in[15];
  const float* fnW    = (const float*)d_in[16];
  const float* fnB    = (const float*)d_in[17];
  float* out = (float*)d_out;

  char* base = (char*)d_ws; size_t off = 0;
  auto alloc = [&](size_t bytes) {
    void* p = base + off; off = (off + bytes + 255) & ~(size_t)255; return p;
  };
  float* h    = (float*)alloc((size_t)T_ * DM * 4);
  u16*   xzt  = (u16*)  alloc((size_t)2 * DI * T_ * 2);   // [1536][T] bf16
  float* dbl  = (float*)alloc((size_t)2 * T_ * 56 * 4);   // double-buffered
  u16*   yt   = (u16*)  alloc((size_t)DI * T_ * 2);       // [DI][T] bf16
  u16*   imcol= (u16*)  alloc((size_t)T_ * 768 * 2);
  u16*   pwB  = (u16*)  alloc((size_t)DM * 768 * 2);
  u16*   inWb = (u16*)  alloc((size_t)DEPTH_ * 2 * DI * DM * 2);
  u16*   xpWb = (u16*)  alloc((size_t)DEPTH_ * 56 * DI * 2);
  u16*   outWb= (u16*)  alloc((size_t)DEPTH_ * DM * DI * 2);

  // one-time (per call) weight conversion fp32 -> bf16, single vectorized launch
  {
    int m0 = DM * 768 / 4;
    int m1 = DEPTH_ * 2 * DI * DM / 4;
    int m2 = DEPTH_ * 56 * DI / 4;
    int m3 = DEPTH_ * DM * DI / 4;
    int mt = m0 + m1 + m2 + m3;
    cvt4v_kernel<<<dim3((mt + 255) / 256), 256, 0, stream>>>(
        patchW, pwB, m0, inW, inWb, m1, xprojW, xpWb, m2, outW, outWb, m3);
  }

  // patch embed: im2col + GEMM + bias/pos (+ zero dbl buffers)
  imcol_kernel<<<dim3(T_ * 768 / 256), 256, 0, stream>>>(z, x, imcol);
  gemm_bf16<<<dim3((T_ + 63) / 64, DM / 64), 256, 0, stream>>>(
      imcol, pwB, h, T_, DM, 768);
  biaspos_kernel<<<dim3(T_ * DM / 256), 256, 0, stream>>>(h, patchB, pos, dbl);

  const int TG = (T_ + 63) / 64;  // 25
  for (int ly = 0; ly < DEPTH_; ++ly) {
    int p = ly & 1;
    float* dblc = dbl + (size_t)p * T_ * 56;
    float* dbln = dbl + (size_t)(p ^ 1) * T_ * 56;
    gemm_ln<<<dim3((2 * DI) / 64, TG), 256, 0, stream>>>(
        h, normW + (size_t)ly * DM, normB + (size_t)ly * DM,
        inWb + (size_t)ly * 2 * DI * DM, xzt);
    xproj_conv<<<dim3(TG, 1, DI / XKC), 256, 0, stream>>>(
        xzt, convW + (size_t)ly * DI * 3, convB + (size_t)ly * DI,
        xpWb + (size_t)ly * 56 * DI, dblc);
    scan_kernel<<<dim3(B_ * DI), 448, 0, stream>>>(
        xzt, dblc, convW + (size_t)ly * DI * 3, convB + (size_t)ly * DI,
        dtW + (size_t)ly * DI * DTR, dtB + (size_t)ly * DI,
        Alog + (size_t)ly * DI * DS, Dpar + (size_t)ly * DI, yt, dbln);
    gemm_out<<<dim3(TG, DM / 64, DI / OKC), 256, 0, stream>>>(
        yt, outWb + (size_t)ly * DM * DI, h);
  }

  ln_kernel<<<dim3(T_), dim3(DM), 0, stream>>>(h, fnW, fnB, out);
}

// Round 9
// 2553.294 us; speedup vs baseline: 1.1581x; 1.1581x over previous
//
#include <hip/hip_runtime.h>

typedef unsigned short u16;
typedef unsigned int   u32;

#define B_     4
#define L_     392
#define T_     1568   // B_*L_
#define DM     384
#define DI     768
#define DS     16
#define DTR    24
#define DEPTH_ 24
#define NPATCH 196
#define NC     28    // scan chunks
#define CL     14    // chunk length (NC*CL == L_)

// xproj_conv: K-split 8 -> 96 d's per block; LDS row pitch 104 (208B = 13*16B)
#define XKC    96
#define XPAD   104
// gemm_out: K-split 2 -> 384 d's per block; LDS row pitch 392 u16 (784B = 49*16B)
#define OKC    384
#define OPAD   392

typedef __bf16 bf16x8 __attribute__((ext_vector_type(8)));
typedef float  f32x4  __attribute__((ext_vector_type(4)));
typedef u16    u16x4  __attribute__((ext_vector_type(4)));

__device__ __forceinline__ u16 f2bf(float f) {
  union { float f; u32 u; } v; v.f = f;
  return (u16)((v.u + 0x7fffu + ((v.u >> 16) & 1u)) >> 16);  // RNE
}
__device__ __forceinline__ float bf2f(u16 h) {
  union { u32 u; float f; } v; v.u = (u32)h << 16; return v.f;
}

// ---------------- fp32 -> bf16 bulk convert, vectorized, 4 segments ----------------
__global__ __launch_bounds__(256) void cvt4v_kernel(const float* __restrict__ s0, u16* __restrict__ o0, int m0,
                                                    const float* __restrict__ s1, u16* __restrict__ o1, int m1,
                                                    const float* __restrict__ s2, u16* __restrict__ o2, int m2,
                                                    const float* __restrict__ s3, u16* __restrict__ o3, int m3) {
  int i = blockIdx.x * 256 + threadIdx.x;   // index in float4 units
  const float* s; u16* o;
  if (i < m0)      { s = s0; o = o0; }
  else { i -= m0;
  if (i < m1)      { s = s1; o = o1; }
  else { i -= m1;
  if (i < m2)      { s = s2; o = o2; }
  else { i -= m2;
  if (i < m3)      { s = s3; o = o3; }
  else return; } } }
  float4 v = ((const float4*)s)[i];
  u16x4 r;
  r.x = f2bf(v.x); r.y = f2bf(v.y); r.z = f2bf(v.z); r.w = f2bf(v.w);
  ((u16x4*)o)[i] = r;
}

// ---------------- im2col for patch embed (both z and x) ----------------
__global__ __launch_bounds__(256) void imcol_kernel(const float* __restrict__ z,
                                                    const float* __restrict__ x,
                                                    u16* __restrict__ out) {
  int idx = blockIdx.x * 256 + threadIdx.x;        // t*768 + k
  int t = idx / 768, k = idx - t * 768;
  int b = t / L_, l = t - b * L_;
  const float* img = (l < NPATCH) ? z : x;
  int p  = (l < NPATCH) ? l : l - NPATCH;
  int py = p / 14, px = p - py * 14;
  int ic = k >> 8, rem = k & 255, i = rem >> 4, j = rem & 15;
  float v = img[((size_t)b * 3 + ic) * 50176 + (size_t)(py * 16 + i) * 224 + (px * 16 + j)];
  out[idx] = f2bf(v);
}

// ---------------- generic bf16 MFMA GEMM (patch embed only) ----------------
__global__ __launch_bounds__(256) void gemm_bf16(const u16* __restrict__ A,
                                                 const u16* __restrict__ W,
                                                 float* __restrict__ outf,
                                                 int M, int N, int K) {
  int wave = threadIdx.x >> 6;
  int lane = threadIdx.x & 63;
  int r = lane & 15, quad = lane >> 4;
  int m_base = blockIdx.x * 64;
  int n_base = blockIdx.y * 64 + wave * 16;

  const u16* aptr[4];
#pragma unroll
  for (int mi = 0; mi < 4; ++mi) {
    int row = m_base + mi * 16 + r; if (row > M - 1) row = M - 1;
    aptr[mi] = A + (size_t)row * K + quad * 8;
  }
  int wcol = n_base + r; if (wcol > N - 1) wcol = N - 1;
  const u16* wptr = W + (size_t)wcol * K + quad * 8;

  f32x4 acc[4] = {f32x4{0,0,0,0}, f32x4{0,0,0,0}, f32x4{0,0,0,0}, f32x4{0,0,0,0}};
  for (int k0 = 0; k0 < K; k0 += 32) {
    bf16x8 bfrag = *(const bf16x8*)(wptr + k0);
#pragma unroll
    for (int mi = 0; mi < 4; ++mi) {
      bf16x8 afrag = *(const bf16x8*)(aptr[mi] + k0);
      acc[mi] = __builtin_amdgcn_mfma_f32_16x16x32_bf16(afrag, bfrag, acc[mi], 0, 0, 0);
    }
  }
  int ccol = n_base + r;
  if (ccol < N) {
#pragma unroll
    for (int mi = 0; mi < 4; ++mi) {
#pragma unroll
      for (int rr = 0; rr < 4; ++rr) {
        int crow = m_base + mi * 16 + quad * 4 + rr;
        if (crow < M) outf[(size_t)crow * N + ccol] = acc[mi][rr];
      }
    }
  }
}

// ---------------- fused LayerNorm + in_proj GEMM ----------------
// xzt[1536][T] = inWb[1536,384] · LN(h)[T,384]^T, bf16 out. grid (24, 25).
__global__ __launch_bounds__(256) void gemm_ln(const float* __restrict__ h,
                                               const float* __restrict__ lw,
                                               const float* __restrict__ lb,
                                               const u16* __restrict__ Wt,
                                               u16* __restrict__ xzt) {
  __shared__ u16 atile[64][392];   // 784B row = 49*16B: aligned b128, 2-way banks
  __shared__ float ps[4][64], ps2[4][64], smu[64], srs[64];
  int tid = threadIdx.x;
  int tok = tid & 63, q = tid >> 6;
  int tok0 = blockIdx.y * 64;
  int tg = tok0 + tok; if (tg > T_ - 1) tg = T_ - 1;
  const float* hrow = h + (size_t)tg * DM + q * 96;

  float s = 0.f, s2 = 0.f;
#pragma unroll
  for (int i = 0; i < 24; ++i) {
    float4 v = *(const float4*)(hrow + i * 4);
    s  += v.x + v.y + v.z + v.w;
    s2 += v.x * v.x + v.y * v.y + v.z * v.z + v.w * v.w;
  }
  ps[q][tok] = s; ps2[q][tok] = s2;
  __syncthreads();
  if (tid < 64) {
    float ts  = ps[0][tid] + ps[1][tid] + ps[2][tid] + ps[3][tid];
    float ts2 = ps2[0][tid] + ps2[1][tid] + ps2[2][tid] + ps2[3][tid];
    float mu  = ts * (1.f / DM);
    float var = ts2 * (1.f / DM) - mu * mu;
    smu[tid] = mu; srs[tid] = rsqrtf(var + 1e-5f);
  }
  __syncthreads();
  {
    float mu = smu[tok], rs = srs[tok];
#pragma unroll
    for (int i = 0; i < 24; ++i) {
      int k = q * 96 + i * 4;
      float4 v  = *(const float4*)(hrow + i * 4);
      float4 w4 = *(const float4*)(lw + k);
      float4 b4 = *(const float4*)(lb + k);
      u16x4 rr;
      rr.x = f2bf((v.x - mu) * rs * w4.x + b4.x);
      rr.y = f2bf((v.y - mu) * rs * w4.y + b4.y);
      rr.z = f2bf((v.z - mu) * rs * w4.z + b4.z);
      rr.w = f2bf((v.w - mu) * rs * w4.w + b4.w);
      *(u16x4*)&atile[tok][k] = rr;
    }
  }
  __syncthreads();

  int lane = tid & 63;
  int r = lane & 15, quad = lane >> 4;
  int m_base = blockIdx.x * 64;
  const u16* aptr[4];
#pragma unroll
  for (int mi = 0; mi < 4; ++mi)
    aptr[mi] = Wt + (size_t)(m_base + mi * 16 + r) * DM + quad * 8;
  const u16* lptr = &atile[q * 16 + r][quad * 8];

  f32x4 acc[4] = {f32x4{0,0,0,0}, f32x4{0,0,0,0}, f32x4{0,0,0,0}, f32x4{0,0,0,0}};
#pragma unroll
  for (int k0 = 0; k0 < DM; k0 += 32) {
    bf16x8 bfrag = *(const bf16x8*)(lptr + k0);
#pragma unroll
    for (int mi = 0; mi < 4; ++mi) {
      bf16x8 afrag = *(const bf16x8*)(aptr[mi] + k0);
      acc[mi] = __builtin_amdgcn_mfma_f32_16x16x32_bf16(afrag, bfrag, acc[mi], 0, 0, 0);
    }
  }
  int ccol = tok0 + q * 16 + r;
  if (ccol < T_) {
#pragma unroll
    for (int mi = 0; mi < 4; ++mi) {
#pragma unroll
      for (int rr2 = 0; rr2 < 4; ++rr2) {
        int crow = m_base + mi * 16 + quad * 4 + rr2;
        xzt[(size_t)crow * T_ + ccol] = f2bf(acc[mi][rr2]);
      }
    }
  }
}

// ---------------- fused conv3+SiLU + x_proj GEMM ----------------
// dbl[T,56] += conv(xzt)·xpW^T over d-slice. grid (25, 1, 8), atomic epilogue.
__global__ __launch_bounds__(256) void xproj_conv(const u16* __restrict__ xzt,
                                                  const float* __restrict__ cw,
                                                  const float* __restrict__ cb,
                                                  const u16* __restrict__ Wx,
                                                  float* __restrict__ dbl) {
  __shared__ u16 tile[64][XPAD];   // 208B row = 13*16B
  int t0 = blockIdx.x * 64;
  int kbeg = blockIdx.z * XKC;
  int tid = threadIdx.x;
  int tl = tid & 63, rq = tid >> 6;
  int t = t0 + tl;
  int tc = (t < T_) ? t : T_ - 1;
  int l = tc % L_;
  for (int kkb = rq * 2; kkb < XKC; kkb += 8) {
    u32 pack = 0;
#pragma unroll
    for (int ss = 0; ss < 2; ++ss) {
      int d = kbeg + kkb + ss;
      const u16* row = xzt + (size_t)d * T_ + tc;
      float acc = cb[d] + cw[d * 3 + 2] * bf2f(row[0]);
      if (l >= 1) acc += cw[d * 3 + 1] * bf2f(row[-1]);
      if (l >= 2) acc += cw[d * 3 + 0] * bf2f(row[-2]);
      float v = acc / (1.f + __expf(-acc));
      pack |= (u32)f2bf(v) << (16 * ss);
    }
    *(u32*)&tile[tl][kkb] = pack;
  }
  __syncthreads();

  int wave = tid >> 6, lane = tid & 63;
  int r = lane & 15, quad = lane >> 4;
  int wcol = wave * 16 + r; int wc = (wcol < 56) ? wcol : 55;
  const u16* wptr = Wx + (size_t)wc * DI + kbeg + quad * 8;

  f32x4 acc4[4] = {f32x4{0,0,0,0}, f32x4{0,0,0,0}, f32x4{0,0,0,0}, f32x4{0,0,0,0}};
#pragma unroll
  for (int k0 = 0; k0 < XKC; k0 += 32) {
    bf16x8 bfrag = *(const bf16x8*)(wptr + k0);
#pragma unroll
    for (int mi = 0; mi < 4; ++mi) {
      bf16x8 afrag = *(const bf16x8*)&tile[mi * 16 + r][k0 + quad * 8];
      acc4[mi] = __builtin_amdgcn_mfma_f32_16x16x32_bf16(afrag, bfrag, acc4[mi], 0, 0, 0);
    }
  }
  if (wcol < 56) {
#pragma unroll
    for (int mi = 0; mi < 4; ++mi) {
#pragma unroll
      for (int rr = 0; rr < 4; ++rr) {
        int crow = t0 + mi * 16 + quad * 4 + rr;
        if (crow < T_) atomicAdd(&dbl[(size_t)crow * 56 + wcol], acc4[mi][rr]);
      }
    }
  }
}

// ---------------- fused transpose + out_proj GEMM ----------------
// h[T,384] += y^T·outW^T over d-slice. grid (25, 6, 2), atomic epilogue.
__global__ __launch_bounds__(256) void gemm_out(const u16* __restrict__ yt,
                                                const u16* __restrict__ Wo,
                                                float* __restrict__ h) {
  __shared__ u16 tile[64][OPAD];
  int t0 = blockIdx.x * 64;
  int n0 = blockIdx.y * 64;
  int kbeg = blockIdx.z * OKC;
  int tid = threadIdx.x;
  {
    int tl2 = tid & 31, rq = tid >> 5;   // 8 rows per pass
    for (int kk = rq; kk < OKC; kk += 8) {
      int d = kbeg + kk;
      u32 v = *(const u32*)(yt + (size_t)d * T_ + t0 + tl2 * 2);
      tile[tl2 * 2][kk]     = (u16)v;
      tile[tl2 * 2 + 1][kk] = (u16)(v >> 16);
    }
  }
  __syncthreads();

  int wave = tid >> 6, lane = tid & 63;
  int r = lane & 15, quad = lane >> 4;
  const u16* wptr = Wo + (size_t)(n0 + wave * 16 + r) * DI + kbeg + quad * 8;

  f32x4 acc[4] = {f32x4{0,0,0,0}, f32x4{0,0,0,0}, f32x4{0,0,0,0}, f32x4{0,0,0,0}};
#pragma unroll
  for (int k0 = 0; k0 < OKC; k0 += 32) {
    bf16x8 bfrag = *(const bf16x8*)(wptr + k0);
#pragma unroll
    for (int mi = 0; mi < 4; ++mi) {
      bf16x8 afrag = *(const bf16x8*)&tile[mi * 16 + r][k0 + quad * 8];
      acc[mi] = __builtin_amdgcn_mfma_f32_16x16x32_bf16(afrag, bfrag, acc[mi], 0, 0, 0);
    }
  }
  int ccol = n0 + wave * 16 + r;
#pragma unroll
  for (int mi = 0; mi < 4; ++mi) {
#pragma unroll
    for (int rr = 0; rr < 4; ++rr) {
      int crow = t0 + mi * 16 + quad * 4 + rr;
      if (crow < T_) atomicAdd(&h[(size_t)crow * DM + ccol], acc[mi][rr]);
    }
  }
}

// ---------------- add patch bias + positional embedding; zero both dbl buffers ----------------
__global__ __launch_bounds__(256) void biaspos_kernel(float* __restrict__ h,
                                                      const float* __restrict__ pb,
                                                      const float* __restrict__ pos,
                                                      float* __restrict__ dblz) {
  int idx = blockIdx.x * 256 + threadIdx.x;  // t*384 + c
  if (idx < 2 * T_ * 56) dblz[idx] = 0.f;
  int t = idx / DM, c = idx - t * DM;
  int p = (t % L_) % NPATCH;
  h[idx] += pb[c] + pos[(size_t)(1 + p) * DM + c];
}

// ---------------- LayerNorm over DM per token (final only) ----------------
__global__ __launch_bounds__(384) void ln_kernel(const float* __restrict__ x,
                                                 const float* __restrict__ w,
                                                 const float* __restrict__ b,
                                                 float* __restrict__ out_f) {
  int t = blockIdx.x;
  int i = threadIdx.x;
  float v = x[(size_t)t * DM + i];
  float s = v, s2 = v * v;
#pragma unroll
  for (int o = 32; o; o >>= 1) { s += __shfl_xor(s, o); s2 += __shfl_xor(s2, o); }
  __shared__ float ls[6], ls2[6];
  int wv = i >> 6;
  if ((i & 63) == 0) { ls[wv] = s; ls2[wv] = s2; }
  __syncthreads();
  float ts = 0.f, ts2 = 0.f;
#pragma unroll
  for (int j = 0; j < 6; ++j) { ts += ls[j]; ts2 += ls2[j]; }
  float mu  = ts * (1.f / DM);
  float var = ts2 * (1.f / DM) - mu * mu;
  float rs  = rsqrtf(var + 1e-5f);
  out_f[(size_t)t * DM + i] = (v - mu) * rs * w[i] + b[i];
}

// ---------------- chunked selective scan v5: NC=28, CL=14, 448 threads ----------------
// Pass B stores h·C partials to LDS (no shfl chains, no lane divergence);
// a cooperative phase reduces over n and writes y coalesced. Recomputes conv row;
// fused dt-proj/softplus + silu(z); dA/dBu register-cached (14 each, no spill).
// Zeroes the NEXT layer's dbl buffer.
__global__ __launch_bounds__(448) void scan_kernel(const u16* __restrict__ xzt,
                                                   const float* __restrict__ dbl,
                                                   const float* __restrict__ cw,
                                                   const float* __restrict__ cb,
                                                   const float* __restrict__ dtW,
                                                   const float* __restrict__ dtB,
                                                   const float* __restrict__ Alog,
                                                   const float* __restrict__ Dp,
                                                   u16* __restrict__ yt,
                                                   float* __restrict__ dblz) {
  int bd = blockIdx.x;          // b*DI + d
  int d  = bd % DI;
  int b  = bd / DI;
  int tid = threadIdx.x;
  int n = tid & 15, c = tid >> 4;   // c in [0,28)

  __shared__ float dtsh[L_];
  __shared__ float zsh[L_];
  __shared__ float xcsh[L_];
  __shared__ float Psh[NC][DS], Ssh[NC][DS], Hsh[NC][DS];
  __shared__ float hC[L_][17];   // pad 17 -> conflict-free column access

  // zero slice of next dbl buffer (29 floats per block)
  {
    int i0 = blockIdx.x * 29 + tid;
    if (tid < 29 && i0 < T_ * 56) dblz[i0] = 0.f;
  }

  // cooperative: conv row (recompute), dt projection + softplus, silu(z) — one pass
  const float* wr = dtW + (size_t)d * DTR;   // block-uniform -> scalar loads
  float bias = dtB[d];
  float w0 = cw[d * 3 + 0], w1 = cw[d * 3 + 1], w2 = cw[d * 3 + 2], cbd = cb[d];
  const u16* xrow = xzt + (size_t)d * T_ + b * L_;
  const u16* zrow = xzt + (size_t)(DI + d) * T_ + b * L_;
  if (tid < L_) {
    int l = tid;
    const float* dr = dbl + (size_t)(b * L_ + l) * 56;
    float s = bias;
#pragma unroll
    for (int j = 0; j < DTR; ++j) s += dr[j] * wr[j];
    dtsh[l] = (s > 20.f) ? s : log1pf(__expf(s));
    float zv = bf2f(zrow[l]);
    zsh[l] = zv / (1.f + __expf(-zv));
    float a = cbd + w2 * bf2f(xrow[l]);
    if (l >= 1) a += w1 * bf2f(xrow[l - 1]);
    if (l >= 2) a += w0 * bf2f(xrow[l - 2]);
    xcsh[l] = a / (1.f + __expf(-a));
  }
  float A  = -__expf(Alog[(size_t)d * DS + n]);
  float Dd = Dp[d];
  __syncthreads();

  int tb = b * L_ + c * CL;
  const float* Bp = dbl + (size_t)tb * 56 + DTR + n;
  const float* Cp = Bp + DS;

  float dA[CL], dBu[CL];
  {
    float P = 1.f, S = 0.f;
#pragma unroll
    for (int l = 0; l < CL; ++l) {
      float dtv = dtsh[c * CL + l];
      float xcv = xcsh[c * CL + l];
      float Bv  = Bp[l * 56];
      float e = __expf(dtv * A);
      float u = dtv * xcv * Bv;
      dA[l] = e; dBu[l] = u;
      P *= e;
      S = e * S + u;
    }
    Psh[c][n] = P; Ssh[c][n] = S;
  }
  __syncthreads();
  if (tid < DS) {   // thread n: serial combine over 28 chunks
    float hh = 0.f;
#pragma unroll
    for (int cc = 0; cc < NC; ++cc) {
      Hsh[cc][tid] = hh;
      hh = Psh[cc][tid] * hh + Ssh[cc][tid];
    }
  }
  __syncthreads();
  {
    float hh = Hsh[c][n];
#pragma unroll
    for (int l = 0; l < CL; ++l) {
      hh = dA[l] * hh + dBu[l];
      hC[c * CL + l][n] = hh * Cp[l * 56];
    }
  }
  __syncthreads();
  if (tid < L_) {   // thread l: reduce over n, gate, coalesced y store
    int l = tid;
    float p = 0.f;
#pragma unroll
    for (int k = 0; k < DS; ++k) p += hC[l][k];
    yt[(size_t)d * T_ + b * L_ + l] = f2bf((p + Dd * xcsh[l]) * zsh[l]);
  }
}

extern "C" void kernel_launch(void* const* d_in, const int* in_sizes, int n_in,
                              void* d_out, int out_size, void* d_ws, size_t ws_size,
                              hipStream_t stream) {
  const float* z      = (const float*)d_in[0];
  const float* x      = (const float*)d_in[1];
  const float* patchW = (const float*)d_in[2];
  const float* patchB = (const float*)d_in[3];
  const float* pos    = (const float*)d_in[4];
  const float* normW  = (const float*)d_in[5];
  const float* normB  = (const float*)d_in[6];
  const float* inW    = (const float*)d_in[7];
  const float* convW  = (const float*)d_in[8];
  const float* convB  = (const float*)d_in[9];
  const float* xprojW = (const float*)d_in[10];
  const float* dtW    = (const float*)d_in[11];
  const float* dtB    = (const float*)d_in[12];
  const float* Alog   = (const float*)d_in[13];
  const float* Dpar   = (const float*)d_in[14];
  const float* outW   = (const float*)d_in[15];
  const float* fnW    = (const float*)d_in[16];
  const float* fnB    = (const float*)d_in[17];
  float* out = (float*)d_out;

  char* base = (char*)d_ws; size_t off = 0;
  auto alloc = [&](size_t bytes) {
    void* p = base + off; off = (off + bytes + 255) & ~(size_t)255; return p;
  };
  float* h    = (float*)alloc((size_t)T_ * DM * 4);
  u16*   xzt  = (u16*)  alloc((size_t)2 * DI * T_ * 2);   // [1536][T] bf16
  float* dbl  = (float*)alloc((size_t)2 * T_ * 56 * 4);   // double-buffered
  u16*   yt   = (u16*)  alloc((size_t)DI * T_ * 2);       // [DI][T] bf16
  u16*   imcol= (u16*)  alloc((size_t)T_ * 768 * 2);
  u16*   pwB  = (u16*)  alloc((size_t)DM * 768 * 2);
  u16*   inWb = (u16*)  alloc((size_t)DEPTH_ * 2 * DI * DM * 2);
  u16*   xpWb = (u16*)  alloc((size_t)DEPTH_ * 56 * DI * 2);
  u16*   outWb= (u16*)  alloc((size_t)DEPTH_ * DM * DI * 2);

  // one-time (per call) weight conversion fp32 -> bf16, single vectorized launch
  {
    int m0 = DM * 768 / 4;
    int m1 = DEPTH_ * 2 * DI * DM / 4;
    int m2 = DEPTH_ * 56 * DI / 4;
    int m3 = DEPTH_ * DM * DI / 4;
    int mt = m0 + m1 + m2 + m3;
    cvt4v_kernel<<<dim3((mt + 255) / 256), 256, 0, stream>>>(
        patchW, pwB, m0, inW, inWb, m1, xprojW, xpWb, m2, outW, outWb, m3);
  }

  // patch embed: im2col + GEMM + bias/pos (+ zero dbl buffers)
  imcol_kernel<<<dim3(T_ * 768 / 256), 256, 0, stream>>>(z, x, imcol);
  gemm_bf16<<<dim3((T_ + 63) / 64, DM / 64), 256, 0, stream>>>(
      imcol, pwB, h, T_, DM, 768);
  biaspos_kernel<<<dim3(T_ * DM / 256), 256, 0, stream>>>(h, patchB, pos, dbl);

  const int TG = (T_ + 63) / 64;  // 25
  for (int ly = 0; ly < DEPTH_; ++ly) {
    int p = ly & 1;
    float* dblc = dbl + (size_t)p * T_ * 56;
    float* dbln = dbl + (size_t)(p ^ 1) * T_ * 56;
    gemm_ln<<<dim3((2 * DI) / 64, TG), 256, 0, stream>>>(
        h, normW + (size_t)ly * DM, normB + (size_t)ly * DM,
        inWb + (size_t)ly * 2 * DI * DM, xzt);
    xproj_conv<<<dim3(TG, 1, DI / XKC), 256, 0, stream>>>(
        xzt, convW + (size_t)ly * DI * 3, convB + (size_t)ly * DI,
        xpWb + (size_t)ly * 56 * DI, dblc);
    scan_kernel<<<dim3(B_ * DI), 448, 0, stream>>>(
        xzt, dblc, convW + (size_t)ly * DI * 3, convB + (size_t)ly * DI,
        dtW + (size_t)ly * DI * DTR, dtB + (size_t)ly * DI,
        Alog + (size_t)ly * DI * DS, Dpar + (size_t)ly * DI, yt, dbln);
    gemm_out<<<dim3(TG, DM / 64, DI / OKC), 256, 0, stream>>>(
        yt, outWb + (size_t)ly * DM * DI, h);
  }

  ln_kernel<<<dim3(T_), dim3(DM), 0, stream>>>(h, fnW, fnB, out);
}